// Round 9
// baseline (42.002 us; speedup 1.0000x reference)
//
#include <hip/hip_runtime.h>
#include <hip/hip_fp16.h>

#define NSTEPS 10
#define D_IN   14400
#define KNN_K  25

// layer dims
#define L0D 7200
#define L1D 3600
#define L2D 1800
#define L3D 900
#define L4D 450
#define NROWS 13950

// 64-row groups per layer; 13 uint2 slots x 64 lanes per group
#define G0 113
#define G1 57
#define G2 29
#define G3 15
#define G4 8
#define SPG 832
#define O1 (G0*SPG)
#define O2 (O1 + G1*SPG)
#define O3 (O2 + G2*SPG)
#define O4 (O3 + G3*SPG)
#define OTOT (O4 + G4*SPG)      // 184704 uint2

#define NPAIR 128
#define NPACK (NPAIR * (D_IN/4))

// 64-aligned half-splits
#define SPLIT0 3584
#define SPLIT1 1792

// f32 -> f16 bits (rn)
__device__ __forceinline__ unsigned f16b(float x) {
    return (unsigned)__half_as_ushort(__float2half_rn(x));
}

// one (idx,w) item: u = (f16_w << 16) | (idx << 2); act entry = half2(b0,b1)
// 3 VALU: and + 2x v_fma_mix_f32 (f16 srcs via op_sel, f32 accum)
__device__ __forceinline__ void gh2(unsigned u, const char* __restrict__ actb,
                                    float& s0, float& s1) {
    const __half2 av = *(const __half2*)(actb + (u & 0xffffu));   // ds_read_b32
    const __half  wh = __ushort_as_half((unsigned short)(u >> 16));
    s0 = fmaf(__half2float(__low2half(av)),  __half2float(wh), s0);
    s1 = fmaf(__half2float(__high2half(av)), __half2float(wh), s1);
}

// ---- prep: (A) bank-permuted lane-major SoA weight tiles (f16 w), (B) pack input half2 ----
__global__ void prep_kernel(const int* __restrict__ k0, const float* __restrict__ w0,
                            const int* __restrict__ k1, const float* __restrict__ w1,
                            const int* __restrict__ k2, const float* __restrict__ w2,
                            const int* __restrict__ k3, const float* __restrict__ w3,
                            const int* __restrict__ k4, const float* __restrict__ w4,
                            const float* __restrict__ input,
                            uint2* __restrict__ tile, uint4* __restrict__ xpk)
{
    const int s = blockIdx.x * 256 + threadIdx.x;
    if (s < NROWS) {
        const int* kp; const float* wp; int dl, obase;
        if      (s < L0D)             { kp = k0; wp = w0; dl = s;             obase = 0;  }
        else if (s < L0D+L1D)         { kp = k1; wp = w1; dl = s - L0D;       obase = O1; }
        else if (s < L0D+L1D+L2D)     { kp = k2; wp = w2; dl = s-L0D-L1D;     obase = O2; }
        else if (s < L0D+L1D+L2D+L3D) { kp = k3; wp = w3; dl = s-L0D-L1D-L2D; obase = O3; }
        else                          { kp = k4; wp = w4; dl = s-L0D-L1D-L2D-L3D; obase = O4; }
        const int g = dl >> 6, l = dl & 63;

        int idx[KNN_K]; float wv[KNN_K]; int bk[KNN_K];
#pragma unroll
        for (int k = 0; k < KNN_K; ++k) {
            idx[k] = kp[dl * KNN_K + k];
            wv[k]  = wp[dl * KNN_K + k];
            bk[k]  = idx[k] & 31;
        }
        const int lm = l - (l >= 50 ? 50 : (l >= 25 ? 25 : 0));   // l % 25
        unsigned* tw = (unsigned*)tile + 2u * (unsigned)(obase + g * SPG);
#pragma unroll
        for (int k = 0; k < KNN_K; ++k) {
            int rank = 0;
#pragma unroll
            for (int j = 0; j < KNN_K; ++j)
                rank += (bk[j] < bk[k]) || (bk[j] == bk[k] && j < k);
            int slot = rank + lm; if (slot >= KNN_K) slot -= KNN_K;
            unsigned u = (f16b(wv[k]) << 16) | ((unsigned)idx[k] << 2);
            tw[((slot >> 1) * 64 + l) * 2 + (slot & 1)] = u;
        }
        tw[(12 * 64 + l) * 2 + 1] = 0;   // pad slot: zero weight, reads act[0]
        return;
    }
    const int t = s - NROWS;
    if (t < NPACK) {
        const int p = t / (D_IN / 4);
        const int c = t - p * (D_IN / 4);
        const float4 a = *(const float4*)(input + ((size_t)(2*p)   * NSTEPS + NSTEPS-1) * D_IN + 4*c);
        const float4 b = *(const float4*)(input + ((size_t)(2*p+1) * NSTEPS + NSTEPS-1) * D_IN + 4*c);
        uint4 wd;
        wd.x = f16b(a.x) | (f16b(b.x) << 16);
        wd.y = f16b(a.y) | (f16b(b.y) << 16);
        wd.z = f16b(a.z) | (f16b(b.z) << 16);
        wd.w = f16b(a.w) | (f16b(b.w) << 16);
        xpk[(size_t)p * (D_IN / 4) + c] = wd;
    }
}

// ---- generic gather sweep over rows [lo,hi) ----
template<int MAXI, int BLK>
__device__ __forceinline__ void glayerG(const char* __restrict__ actb,
                                        unsigned* __restrict__ yout,
                                        const uint2* __restrict__ tb,
                                        const float* __restrict__ bias,
                                        int lo, int hi, int tid)
{
#pragma unroll
    for (int i = 0; i < MAXI; ++i) {
        int r = lo + tid + i * BLK;
        if (r < hi) {
            const uint2* tp = tb + (size_t)(r >> 6) * SPG + (r & 63);
            float a0 = bias[r], a1 = a0, c0 = 0.f, c1 = 0.f;
#pragma unroll
            for (int j = 0; j < 13; ++j) {
                uint2 u = tp[j * 64];          // coalesced 512B/wave, L2-resident
                gh2(u.x, actb, a0, a1);
                gh2(u.y, actb, c0, c1);
            }
            a0 += c0; a1 += c1;
            yout[r] = f16b(a0) | (f16b(a1) << 16);
        }
    }
}

// ---- layer 0: 256 blocks = 128 pairs x 2 neuron-halves ----
__global__ __launch_bounds__(512, 2)
void lcn_l0(const uint4* __restrict__ xpk, const uint2* __restrict__ tile,
            const float* __restrict__ b0, unsigned* __restrict__ y0)
{
    __shared__ unsigned act[D_IN];             // 57.6 KB -> 2 blocks/CU
    const int tid = threadIdx.x;
    const int p   = blockIdx.x & 127;
    const int h   = blockIdx.x >> 7;

    const uint4* src = xpk + (size_t)p * (D_IN / 4);
    for (int i = tid; i < D_IN / 4; i += 512)
        *(uint4*)(act + 4 * i) = src[i];
    __syncthreads();

    glayerG<8, 512>((const char*)act, y0 + (size_t)p * L0D, tile, b0,
                    h ? SPLIT0 : 0, h ? L0D : SPLIT0, tid);
}

// ---- layer 1: 256 blocks = 128 pairs x 2 neuron-halves ----
__global__ __launch_bounds__(512, 2)
void lcn_l1(const unsigned* __restrict__ y0, const uint2* __restrict__ tile,
            const float* __restrict__ b1, unsigned* __restrict__ y1)
{
    __shared__ unsigned act[L0D];              // 28.8 KB
    const int tid = threadIdx.x;
    const int p   = blockIdx.x & 127;
    const int h   = blockIdx.x >> 7;

    const uint4* src = (const uint4*)(y0 + (size_t)p * L0D);
    for (int i = tid; i < L0D / 4; i += 512)
        *(uint4*)(act + 4 * i) = src[i];
    __syncthreads();

    glayerG<4, 512>((const char*)act, y1 + (size_t)p * L1D, tile + O1, b1,
                    h ? SPLIT1 : 0, h ? L1D : SPLIT1, tid);
}

// ---- tail: L2..L4 + FC, 256 blocks (pair x batch-half), redundant L2-L4 compute ----
__global__ __launch_bounds__(1024)
void lcn_tail(const unsigned* __restrict__ y1, const uint2* __restrict__ tile,
              const float* __restrict__ b2, const float* __restrict__ b3,
              const float* __restrict__ b4,
              const float* __restrict__ fc_w, const float* __restrict__ fc_b,
              float* __restrict__ out)
{
    __shared__ unsigned sm[L1D + L2D + L3D];   // 25.2 KB
    __shared__ float y4[L4D];                  // 1.8 KB
    const int tid = threadIdx.x;
    const int p   = blockIdx.x & 127;
    const int h   = blockIdx.x >> 7;           // batch within pair

    const uint4* src = (const uint4*)(y1 + (size_t)p * L1D);
    if (tid < L1D / 4) *(uint4*)(sm + 4 * tid) = src[tid];
    __syncthreads();

    // L2: read sm[0:3600) -> write sm[3600:5400)
    glayerG<2, 1024>((const char*)sm, sm + L1D, tile + O2, b2, 0, L2D, tid);
    __syncthreads();
    // L3: read sm[3600:5400) -> write sm[5400:6300)
    glayerG<1, 1024>((const char*)(sm + L1D), sm + L1D + L2D, tile + O3, b3, 0, L3D, tid);
    __syncthreads();
    // L4: read sm[5400:6300) -> keep own batch in f32
    if (tid < L4D) {
        const uint2* tp = tile + O4 + (size_t)(tid >> 6) * SPG + (tid & 63);
        const char* actb = (const char*)(sm + L1D + L2D);
        float a0 = b4[tid], a1 = a0, c0 = 0.f, c1 = 0.f;
#pragma unroll
        for (int j = 0; j < 13; ++j) {
            uint2 u = tp[j * 64];
            gh2(u.x, actb, a0, a1);
            gh2(u.y, actb, c0, c1);
        }
        a0 += c0; a1 += c1;
        y4[tid] = h ? a1 : a0;
    }
    __syncthreads();

    // FC: 2 waves, one per output channel, batch = 2p+h
    if (tid < 128) {
        const int o = tid >> 6, lane = tid & 63;
        float s = 0.f;
#pragma unroll
        for (int it = 0; it < 8; ++it) {
            int r = lane + it * 64;
            if (r < L4D) s += y4[r] * fc_w[o * L4D + r];
        }
#pragma unroll
        for (int off = 32; off > 0; off >>= 1) s += __shfl_xor(s, off);
        if (lane == 0) out[(2 * p + h) * 2 + o] = s + fc_b[o];
    }
}

extern "C" void kernel_launch(void* const* d_in, const int* in_sizes, int n_in,
                              void* d_out, int out_size, void* d_ws, size_t ws_size,
                              hipStream_t stream) {
    const float* input = (const float*)d_in[0];
    const int*   knn[5];
    const float* w[5];
    const float* bias[5];
    for (int i = 0; i < 5; ++i) {
        knn[i]  = (const int*)  d_in[1 + 3 * i];
        w[i]    = (const float*)d_in[2 + 3 * i];
        bias[i] = (const float*)d_in[3 + 3 * i];
    }
    const float* fc_w = (const float*)d_in[16];
    const float* fc_b = (const float*)d_in[17];
    float* out = (float*)d_out;

    // ws layout (16B-aligned): tile | xpk | y0 | y1
    char* base = (char*)d_ws;
    uint2*    tile = (uint2*)base;                                        // 1.478 MB
    uint4*    xpk  = (uint4*)(base + (size_t)OTOT * 8);                   // 7.373 MB
    unsigned* y0   = (unsigned*)((char*)xpk + (size_t)NPAIR * D_IN * 4);  // 3.686 MB
    unsigned* y1   = y0 + (size_t)NPAIR * L0D;                            // 1.843 MB

    const int nprep = NROWS + NPACK;
    prep_kernel<<<(nprep + 255) / 256, 256, 0, stream>>>(
        knn[0], w[0], knn[1], w[1], knn[2], w[2], knn[3], w[3], knn[4], w[4],
        input, tile, xpk);

    lcn_l0<<<256, 512, 0, stream>>>(xpk, tile, bias[0], y0);
    lcn_l1<<<256, 512, 0, stream>>>(y0, tile, bias[1], y1);
    lcn_tail<<<256, 1024, 0, stream>>>(y1, tile, bias[2], bias[3], bias[4],
                                       fc_w, fc_b, out);
}

// Round 10
// 40.424 us; speedup vs baseline: 1.0390x; 1.0390x over previous
//
#include <hip/hip_runtime.h>
#include <hip/hip_fp16.h>

#define NSTEPS 10
#define D_IN   14400
#define KNN_K  25

// layer dims
#define L0D 7200
#define L1D 3600
#define L2D 1800
#define L3D 900
#define L4D 450
#define NROWS 13950

// 64-row groups per layer; 13 uint2 slots x 64 lanes per group
#define G0 113
#define G1 57
#define G2 29
#define G3 15
#define G4 8
#define SPG 832
#define O1 (G0*SPG)
#define O2 (O1 + G1*SPG)
#define O3 (O2 + G2*SPG)
#define O4 (O3 + G3*SPG)
#define OTOT (O4 + G4*SPG)      // 184704 uint2 = 1.478 MB

#define NPAIR 128

// f32 -> f16 bits (rn)
__device__ __forceinline__ unsigned f16b(float x) {
    return (unsigned)__half_as_ushort(__float2half_rn(x));
}

// one (idx,w) item: u = (f16_w << 16) | (byte_off); act entry = half2(b0,b1)
// 3 VALU: and + 2x v_fma_mix_f32
__device__ __forceinline__ void gh2(unsigned u, const char* __restrict__ actb,
                                    float& s0, float& s1) {
    const __half2 av = *(const __half2*)(actb + (u & 0xffffu));   // ds_read_b32
    const __half  wh = __ushort_as_half((unsigned short)(u >> 16));
    s0 = fmaf(__half2float(__low2half(av)),  __half2float(wh), s0);
    s1 = fmaf(__half2float(__high2half(av)), __half2float(wh), s1);
}

// ---- prep: bank-permuted lane-major SoA weight tiles (f16 weights, byte offsets) ----
__global__ void prep_kernel(const int* __restrict__ k0, const float* __restrict__ w0,
                            const int* __restrict__ k1, const float* __restrict__ w1,
                            const int* __restrict__ k2, const float* __restrict__ w2,
                            const int* __restrict__ k3, const float* __restrict__ w3,
                            const int* __restrict__ k4, const float* __restrict__ w4,
                            uint2* __restrict__ tile)
{
    const int s = blockIdx.x * 256 + threadIdx.x;
    if (s >= NROWS) return;
    const int* kp; const float* wp; int dl, obase;
    if      (s < L0D)             { kp = k0; wp = w0; dl = s;             obase = 0;  }
    else if (s < L0D+L1D)         { kp = k1; wp = w1; dl = s - L0D;       obase = O1; }
    else if (s < L0D+L1D+L2D)     { kp = k2; wp = w2; dl = s-L0D-L1D;     obase = O2; }
    else if (s < L0D+L1D+L2D+L3D) { kp = k3; wp = w3; dl = s-L0D-L1D-L2D; obase = O3; }
    else                          { kp = k4; wp = w4; dl = s-L0D-L1D-L2D-L3D; obase = O4; }
    const int g = dl >> 6, l = dl & 63;

    int idx[KNN_K]; float wv[KNN_K]; int bk[KNN_K];
#pragma unroll
    for (int k = 0; k < KNN_K; ++k) {
        idx[k] = kp[dl * KNN_K + k];
        wv[k]  = wp[dl * KNN_K + k];
        bk[k]  = idx[k] & 31;
    }
    const int lm = l - (l >= 50 ? 50 : (l >= 25 ? 25 : 0));   // l % 25
    unsigned* tw = (unsigned*)tile + 2u * (unsigned)(obase + g * SPG);
#pragma unroll
    for (int k = 0; k < KNN_K; ++k) {
        int rank = 0;
#pragma unroll
        for (int j = 0; j < KNN_K; ++j)
            rank += (bk[j] < bk[k]) || (bk[j] == bk[k] && j < k);
        int slot = rank + lm; if (slot >= KNN_K) slot -= KNN_K;
        unsigned u = (f16b(wv[k]) << 16) | ((unsigned)idx[k] << 2);
        tw[((slot >> 1) * 64 + l) * 2 + (slot & 1)] = u;
    }
    tw[(12 * 64 + l) * 2 + 1] = 0;   // pad slot: zero weight, reads act[0]
}

// ---- one gather layer: rows [0,DIM), act region -> out region (both LDS) ----
template<int DIM>
__device__ __forceinline__ void glayer(const unsigned* __restrict__ actw,
                                       unsigned* __restrict__ yout,
                                       const uint2* __restrict__ tb,
                                       const float* __restrict__ bias, int tid)
{
    const char* actb = (const char*)actw;
    for (int r = tid; r < DIM; r += 1024) {
        const uint2* tp = tb + (size_t)(r >> 6) * SPG + (r & 63);
        float a0 = bias[r], a1 = a0, c0 = 0.f, c1 = 0.f;
#pragma unroll
        for (int j = 0; j < 13; ++j) {
            uint2 u = tp[j * 64];          // coalesced 512B/wave, L2-resident
            gh2(u.x, actb, a0, a1);
            gh2(u.y, actb, c0, c1);
        }
        a0 += c0; a1 += c1;
        yout[r] = f16b(a0) | (f16b(a1) << 16);
    }
    __syncthreads();
}

// ---- mono kernel: one block per batch-pair, whole network in LDS, no cross-block deps ----
__global__ __launch_bounds__(1024, 1)
void lcn_mono(const float* __restrict__ input, const uint2* __restrict__ tile,
              const float* __restrict__ b0, const float* __restrict__ b1,
              const float* __restrict__ b2, const float* __restrict__ b3,
              const float* __restrict__ b4,
              const float* __restrict__ fc_w, const float* __restrict__ fc_b,
              float* __restrict__ out)
{
    __shared__ unsigned sm[D_IN + L0D];      // 86.4 KB -> 1 block/CU, 16 waves
    unsigned* X  = sm;                       // [0, 14400)       input, dead after L0
    unsigned* Y0 = sm + D_IN;                // [14400, 21600)
    unsigned* Y1 = sm;                       // [0, 3600)        over X
    unsigned* Y2 = sm + 3600;                // [3600, 5400)
    unsigned* Y3 = sm + 5400;                // [5400, 6300)
    unsigned* Y4 = sm + 6300;                // [6300, 6750)     packed f16 pair

    const int tid = threadIdx.x;
    const int p   = blockIdx.x;

    // ---- stage input pair (rows 2p, 2p+1, last step) f32 -> f16x2 LDS ----
    {
        const float4* r0 = (const float4*)(input + ((size_t)(2 * p)     * NSTEPS + NSTEPS - 1) * D_IN);
        const float4* r1 = (const float4*)(input + ((size_t)(2 * p + 1) * NSTEPS + NSTEPS - 1) * D_IN);
        for (int i = tid; i < D_IN / 4; i += 1024) {
            float4 a = r0[i], b = r1[i];
            uint4 wd;
            wd.x = f16b(a.x) | (f16b(b.x) << 16);
            wd.y = f16b(a.y) | (f16b(b.y) << 16);
            wd.z = f16b(a.z) | (f16b(b.z) << 16);
            wd.w = f16b(a.w) | (f16b(b.w) << 16);
            *(uint4*)(X + 4 * i) = wd;
        }
    }
    __syncthreads();

    glayer<L0D>(X,  Y0, tile,      b0, tid);   // L0: X -> Y0
    glayer<L1D>(Y0, Y1, tile + O1, b1, tid);   // L1: Y0 -> Y1 (over X, X dead)
    glayer<L2D>(Y1, Y2, tile + O2, b2, tid);   // L2
    glayer<L3D>(Y2, Y3, tile + O3, b3, tid);   // L3
    glayer<L4D>(Y3, Y4, tile + O4, b4, tid);   // L4

    // ---- FC: 4 waves -> (out o, batch-in-pair j) ----
    if (tid < 256) {
        const int wv = tid >> 6, lane = tid & 63;
        const int o = wv >> 1, j = wv & 1;
        float s = 0.f;
#pragma unroll
        for (int it = 0; it < 8; ++it) {
            int r = lane + it * 64;
            if (r < L4D) {
                unsigned av = Y4[r];
                const __half2 h2 = *(const __half2*)&av;
                float xv = __half2float(j ? __high2half(h2) : __low2half(h2));
                s += xv * fc_w[o * L4D + r];
            }
        }
#pragma unroll
        for (int off = 32; off > 0; off >>= 1) s += __shfl_xor(s, off);
        if (lane == 0) out[(2 * p + j) * 2 + o] = s + fc_b[o];
    }
}

extern "C" void kernel_launch(void* const* d_in, const int* in_sizes, int n_in,
                              void* d_out, int out_size, void* d_ws, size_t ws_size,
                              hipStream_t stream) {
    const float* input = (const float*)d_in[0];
    const int*   knn[5];
    const float* w[5];
    const float* bias[5];
    for (int i = 0; i < 5; ++i) {
        knn[i]  = (const int*)  d_in[1 + 3 * i];
        w[i]    = (const float*)d_in[2 + 3 * i];
        bias[i] = (const float*)d_in[3 + 3 * i];
    }
    const float* fc_w = (const float*)d_in[16];
    const float* fc_b = (const float*)d_in[17];
    float* out = (float*)d_out;

    uint2* tile = (uint2*)d_ws;    // 1.478 MB

    prep_kernel<<<(NROWS + 255) / 256, 256, 0, stream>>>(
        knn[0], w[0], knn[1], w[1], knn[2], w[2], knn[3], w[3], knn[4], w[4], tile);

    lcn_mono<<<NPAIR, 1024, 0, stream>>>(
        input, tile, bias[0], bias[1], bias[2], bias[3], bias[4],
        fc_w, fc_b, out);
}

// Round 11
// 38.523 us; speedup vs baseline: 1.0903x; 1.0493x over previous
//
#include <hip/hip_runtime.h>
#include <hip/hip_fp16.h>

#define NSTEPS 10
#define D_IN   14400
#define KNN_K  25

#define L0D 7200
#define L1D 3600
#define L2D 1800
#define L3D 900
#define L4D 450
#define NROWS 13950

// row-major weight table offsets (global row id * 25)
#define WT2 (10800 * KNN_K)
#define WT3 (12600 * KNN_K)
#define WT4 (13500 * KNN_K)

#define NPAIR 128

__device__ __forceinline__ unsigned f16b(float x) {
    return (unsigned)__half_as_ushort(__float2half_rn(x));
}

// ---- node 1: input transpose (batch-major f16) + weight pack (row-major u32) ----
__global__ void prep_kernel(const float* __restrict__ input,
                            const int* __restrict__ k0, const float* __restrict__ w0,
                            const int* __restrict__ k1, const float* __restrict__ w1,
                            const int* __restrict__ k2, const float* __restrict__ w2,
                            const int* __restrict__ k3, const float* __restrict__ w3,
                            const int* __restrict__ k4, const float* __restrict__ w4,
                            unsigned* __restrict__ wt, __half* __restrict__ X0)
{
    const int bid = blockIdx.x;
    if (bid < 900) {
        // transpose a 64x64 tile of input[:, 9, :] -> X0[feature][batch] f16
        __shared__ float tile[64][65];
        const int bx = bid % 225, by = bid / 225;
        const int d0 = bx * 64, b0 = by * 64;
        const int tx = threadIdx.x & 63, ty = threadIdx.x >> 6;
#pragma unroll
        for (int i = 0; i < 16; ++i) {
            const int bl = ty * 16 + i;
            tile[bl][tx] = input[(size_t)(b0 + bl) * (NSTEPS * D_IN) + (size_t)(NSTEPS - 1) * D_IN + d0 + tx];
        }
        __syncthreads();
#pragma unroll
        for (int i = 0; i < 16; ++i) {
            const int dl = ty * 16 + i;
            X0[(size_t)(d0 + dl) * 256 + b0 + tx] = __float2half_rn(tile[tx][dl]);
        }
        return;
    }
    // weight pack: u = (f16_w << 16) | idx
    const int t = (bid - 900) * 256 + threadIdx.x;
    if (t >= NROWS * KNN_K) return;
    const int row = t / KNN_K;
    const int k   = t - row * KNN_K;
    const int* kp; const float* wp; int dl;
    if      (row < 7200)  { kp = k0; wp = w0; dl = row; }
    else if (row < 10800) { kp = k1; wp = w1; dl = row - 7200; }
    else if (row < 12600) { kp = k2; wp = w2; dl = row - 10800; }
    else if (row < 13500) { kp = k3; wp = w3; dl = row - 12600; }
    else                  { kp = k4; wp = w4; dl = row - 13500; }
    const int   idx = kp[dl * KNN_K + k];
    const float wv  = wp[dl * KNN_K + k];
    wt[t] = (f16b(wv) << 16) | (unsigned)idx;
}

// ---- node 2: L0 wide. one wave per row, lane owns 4 batches, 512B block-gathers from L2 ----
__global__ __launch_bounds__(512)
void lcn_l0(const __half* __restrict__ X, const unsigned* __restrict__ wt,
            const float* __restrict__ bias, __half* __restrict__ Y)
{
    const int lane = threadIdx.x & 63;
    const int row  = blockIdx.x * 8 + (threadIdx.x >> 6);
    const int srow = __builtin_amdgcn_readfirstlane(row);     // wave-uniform -> s_loads
    const unsigned* __restrict__ wr = wt + (size_t)srow * KNN_K;
    const float bv = bias[srow];
    float a0 = bv, a1 = bv, a2 = bv, a3 = bv;
    const int boff = lane * 4;
#pragma unroll
    for (int k = 0; k < KNN_K; ++k) {
        const unsigned u = wr[k];                             // scalar load (uniform)
        const uint2 xv = *(const uint2*)(X + (size_t)(u & 0x3fffu) * 256 + boff);
        const float wf = __half2float(__ushort_as_half((unsigned short)(u >> 16)));
        const __half2 x01 = *(const __half2*)&xv.x;
        const __half2 x23 = *(const __half2*)&xv.y;
        a0 = fmaf(__half2float(__low2half(x01)),  wf, a0);    // v_fma_mix_f32
        a1 = fmaf(__half2float(__high2half(x01)), wf, a1);
        a2 = fmaf(__half2float(__low2half(x23)),  wf, a2);
        a3 = fmaf(__half2float(__high2half(x23)), wf, a3);
    }
    uint2 o;
    o.x = f16b(a0) | (f16b(a1) << 16);
    o.y = f16b(a2) | (f16b(a3) << 16);
    *(uint2*)(Y + (size_t)srow * 256 + boff) = o;
}

// ---- node 3: L1 wide, same gather, but writes PAIR-MAJOR Y1p[pair][3600] for the tail ----
__global__ __launch_bounds__(512)
void lcn_l1(const __half* __restrict__ X, const unsigned* __restrict__ wt,
            const float* __restrict__ bias, unsigned* __restrict__ Y1p)
{
    const int lane = threadIdx.x & 63;
    const int row  = blockIdx.x * 8 + (threadIdx.x >> 6);
    const int srow = __builtin_amdgcn_readfirstlane(row);
    const unsigned* __restrict__ wr = wt + (size_t)(7200 + srow) * KNN_K;
    const float bv = bias[srow];
    float a0 = bv, a1 = bv, a2 = bv, a3 = bv;
    const int boff = lane * 4;
#pragma unroll
    for (int k = 0; k < KNN_K; ++k) {
        const unsigned u = wr[k];
        const uint2 xv = *(const uint2*)(X + (size_t)(u & 0x3fffu) * 256 + boff);
        const float wf = __half2float(__ushort_as_half((unsigned short)(u >> 16)));
        const __half2 x01 = *(const __half2*)&xv.x;
        const __half2 x23 = *(const __half2*)&xv.y;
        a0 = fmaf(__half2float(__low2half(x01)),  wf, a0);
        a1 = fmaf(__half2float(__high2half(x01)), wf, a1);
        a2 = fmaf(__half2float(__low2half(x23)),  wf, a2);
        a3 = fmaf(__half2float(__high2half(x23)), wf, a3);
    }
    // lane owns batches 4l..4l+3 = pairs 2l, 2l+1
    Y1p[(size_t)(2 * lane)     * L1D + srow] = f16b(a0) | (f16b(a1) << 16);
    Y1p[(size_t)(2 * lane + 1) * L1D + srow] = f16b(a2) | (f16b(a3) << 16);
}

// ---- tail helper: one LDS gather layer (per-thread rows, 2 batches per word) ----
__device__ __forceinline__ void tlayer(const unsigned* __restrict__ src,
                                       unsigned* __restrict__ dst,
                                       const unsigned* __restrict__ wbase,
                                       const float* __restrict__ bias,
                                       int dim, int tid)
{
    for (int r = tid; r < dim; r += 1024) {
        const unsigned* wr = wbase + (size_t)r * KNN_K;
        const float bv = bias[r];
        float a0 = bv, a1 = bv;
#pragma unroll
        for (int k = 0; k < KNN_K; ++k) {
            const unsigned u  = wr[k];
            const unsigned av = src[u & 0x3fffu];
            const float wf = __half2float(__ushort_as_half((unsigned short)(u >> 16)));
            const __half2 h = *(const __half2*)&av;
            a0 = fmaf(__half2float(__low2half(h)),  wf, a0);
            a1 = fmaf(__half2float(__high2half(h)), wf, a1);
        }
        dst[r] = f16b(a0) | (f16b(a1) << 16);
    }
}

// ---- node 4: tail. one block per batch-pair: L2,L3,L4 in LDS + FC ----
__global__ __launch_bounds__(1024)
void lcn_tail(const unsigned* __restrict__ Y1p, const unsigned* __restrict__ wt,
              const float* __restrict__ b2, const float* __restrict__ b3,
              const float* __restrict__ b4,
              const float* __restrict__ fc_w, const float* __restrict__ fc_b,
              float* __restrict__ out)
{
    __shared__ unsigned sm[L1D + L2D + L3D + L4D];   // 27 KB
    unsigned* R1 = sm;
    unsigned* R2 = sm + L1D;
    unsigned* R3 = R2 + L2D;
    unsigned* R4 = R3 + L3D;
    const int tid = threadIdx.x;
    const int p   = blockIdx.x;

    // coalesced stage-in of this pair's L1 activations
    for (int d = tid; d < L1D; d += 1024)
        R1[d] = Y1p[(size_t)p * L1D + d];
    __syncthreads();

    tlayer(R1, R2, wt + WT2, b2, L2D, tid);
    __syncthreads();
    tlayer(R2, R3, wt + WT3, b3, L3D, tid);
    __syncthreads();
    tlayer(R3, R4, wt + WT4, b4, L4D, tid);
    __syncthreads();

    // FC: 4 waves -> (out o, batch-in-pair j)
    if (tid < 256) {
        const int wv = tid >> 6, lane = tid & 63;
        const int o = wv >> 1, j = wv & 1;
        float s = 0.f;
#pragma unroll
        for (int it = 0; it < 8; ++it) {
            const int r = lane + it * 64;
            if (r < L4D) {
                const unsigned av = R4[r];
                const __half2 h = *(const __half2*)&av;
                s += __half2float(j ? __high2half(h) : __low2half(h)) * fc_w[o * L4D + r];
            }
        }
#pragma unroll
        for (int off = 32; off > 0; off >>= 1) s += __shfl_xor(s, off);
        if (lane == 0) out[(2 * p + j) * 2 + o] = s + fc_b[o];
    }
}

extern "C" void kernel_launch(void* const* d_in, const int* in_sizes, int n_in,
                              void* d_out, int out_size, void* d_ws, size_t ws_size,
                              hipStream_t stream) {
    const float* input = (const float*)d_in[0];
    const int*   knn[5];
    const float* w[5];
    const float* bias[5];
    for (int i = 0; i < 5; ++i) {
        knn[i]  = (const int*)  d_in[1 + 3 * i];
        w[i]    = (const float*)d_in[2 + 3 * i];
        bias[i] = (const float*)d_in[3 + 3 * i];
    }
    const float* fc_w = (const float*)d_in[16];
    const float* fc_b = (const float*)d_in[17];
    float* out = (float*)d_out;

    // ws layout (16B-aligned): X0 | Y0 | Y1p | wt
    char* base = (char*)d_ws;
    __half*   X0  = (__half*)base;                                   // 7.373 MB
    __half*   Y0  = (__half*)(base + (size_t)D_IN * 256 * 2);        // 3.686 MB
    unsigned* Y1p = (unsigned*)((char*)Y0 + (size_t)L0D * 256 * 2);  // 1.843 MB
    unsigned* wt  = (unsigned*)((char*)Y1p + (size_t)NPAIR * L1D * 4); // 1.395 MB

    const int npack_blocks = (NROWS * KNN_K + 255) / 256;            // 1363
    prep_kernel<<<900 + npack_blocks, 256, 0, stream>>>(
        input, knn[0], w[0], knn[1], w[1], knn[2], w[2], knn[3], w[3], knn[4], w[4],
        wt, X0);

    lcn_l0<<<L0D / 8, 512, 0, stream>>>(X0, wt, bias[0], Y0);
    lcn_l1<<<L1D / 8, 512, 0, stream>>>(Y0, wt + 0, bias[1], Y1p);   // wr offset handled inside
    lcn_tail<<<NPAIR, 1024, 0, stream>>>(Y1p, wt, bias[2], bias[3], bias[4],
                                         fc_w, fc_b, out);
}